// Round 4
// baseline (1273.864 us; speedup 1.0000x reference)
//
#include <hip/hip_runtime.h>

#define HW 4096
#define CC 256
#define KK 2048
#define BB 16
#define NN (BB*HW)          // 65536
#define ROWS 8

// d_out layout (floats): [z_q 16777216][idx 65536][loss 1][probs 134217728]
#define ZQ_SZ   (BB*CC*HW)          // 16777216
#define IDX_OFF ZQ_SZ
#define LOSS_OFF (IDX_OFF + NN)     // 16842752
#define PROBS_OFF (LOSS_OFF + 1)    // 16842753 (only 4B-aligned!)
// scratch parked inside the z_q region (overwritten by k_zq at the end):
#define CT_OFF 0                    // ct[C][K] transposed codebook, 2MB
#define EE_OFF (CC*KK)              // ee[K]
#define ZZ_OFF 1048576              // zz[N]

// ---- numpy pairwise sum-of-squares over 256 elements (PW_BLOCKSIZE=128) ----
template<int STRIDE>
__device__ __forceinline__ float np_sumsq256(const float* __restrict__ a){
  float res0 = 0.f, res1 = 0.f;
  #pragma unroll
  for (int h = 0; h < 2; h++){
    const float* p = a + (size_t)h * 128 * STRIDE;
    float r[8];
    #pragma unroll
    for (int j = 0; j < 8; j++){ float x = p[(size_t)j * STRIDE]; r[j] = __fmul_rn(x, x); }
    for (int i = 8; i < 128; i += 8){
      #pragma unroll
      for (int j = 0; j < 8; j++){
        float x = p[(size_t)(i + j) * STRIDE];
        r[j] = __fadd_rn(r[j], __fmul_rn(x, x));
      }
    }
    float s = __fadd_rn(__fadd_rn(__fadd_rn(r[0], r[1]), __fadd_rn(r[2], r[3])),
                        __fadd_rn(__fadd_rn(r[4], r[5]), __fadd_rn(r[6], r[7])));
    if (h == 0) res0 = s; else res1 = s;
  }
  return __fadd_rn(res0, res1);
}

// ---------------- codebook transpose: ct[c][k] = cb[k][c] ----------------
__global__ void k_prep(const float* __restrict__ cb, float* __restrict__ out){
  __shared__ float tile[64][65];
  const int t = threadIdx.x;            // 256
  const int lane = t & 63, q = t >> 6;
  const int bk = blockIdx.x & 31;
  const int bc = blockIdx.x >> 5;
  const int k0 = bk * 64, c0 = bc * 64;
  #pragma unroll
  for (int j = 0; j < 16; j++){
    int kr = q * 16 + j;
    tile[kr][lane] = cb[(size_t)(k0 + kr) * CC + c0 + lane];
  }
  __syncthreads();
  float* ct = out + CT_OFF;
  #pragma unroll
  for (int j = 0; j < 16; j++){
    int cr = q * 16 + j;
    ct[(size_t)(c0 + cr) * KK + k0 + lane] = tile[lane][cr];
  }
}

// ---------------- ee[k] = np-pairwise sum_c cb[k][c]^2 ----------------
__global__ void k_ee(const float* __restrict__ cb, float* __restrict__ out){
  const int k = blockIdx.x * 256 + threadIdx.x;  // 8 blocks -> 2048
  out[EE_OFF + k] = np_sumsq256<1>(cb + (size_t)k * CC);
}

// ---------------- zz[n] = np-pairwise sum_c feats[b][c][hw]^2 ----------------
__global__ void k_zz(const float* __restrict__ feats, float* __restrict__ out){
  const int n = blockIdx.x * 256 + threadIdx.x;  // 256 blocks -> 65536
  const int b = n >> 12, hw = n & 4095;
  out[ZZ_OFF + n] = np_sumsq256<HW>(feats + (size_t)b * CC * HW + hw);
}

// macro-hygiene: scalar param named zv_ so it can't collide with .x/.y/.z/.w tokens
#define ROW_FMA(r, zv_, cvv) \
  acc[r][0] = __builtin_fmaf(zv_, cvv.x, acc[r][0]); \
  acc[r][1] = __builtin_fmaf(zv_, cvv.y, acc[r][1]); \
  acc[r][2] = __builtin_fmaf(zv_, cvv.z, acc[r][2]); \
  acc[r][3] = __builtin_fmaf(zv_, cvv.w, acc[r][3]);

#define FMA_STEP(cvv, zaa, zbb) \
  ROW_FMA(0, zaa.x, cvv) ROW_FMA(1, zaa.y, cvv) ROW_FMA(2, zaa.z, cvv) ROW_FMA(3, zaa.w, cvv) \
  ROW_FMA(4, zbb.x, cvv) ROW_FMA(5, zbb.y, cvv) ROW_FMA(6, zbb.z, cvv) ROW_FMA(7, zbb.w, cvv)

// ---------------- main: d (np-fp32-bit-exact), argmin, softmax probs, loss ----------------
__global__ __launch_bounds__(512, 6)
void k_main(const float* __restrict__ feats, const float* __restrict__ cb, float* out){
  __shared__ float zt[CC][ROWS];     // 8KB
  __shared__ float zzs[ROWS];
  __shared__ float minv_s[ROWS];
  __shared__ float red_v[ROWS][8];
  __shared__ int   red_k[ROWS][8];
  __shared__ float red_s[ROWS][8];
  __shared__ float sum_s[ROWS];
  __shared__ int   finidx[ROWS];
  __shared__ float lred[ROWS];

  const int t   = threadIdx.x;
  const int blk = blockIdx.x;          // 8192
  const int bi  = blk >> 9;            // image index
  const int hw0 = (blk & 511) * ROWS;  // pixel base
  const int row0 = bi * HW + hw0;
  const int wv = t >> 6, lane = t & 63;

  // ---- stage z rows: zt[c][r] = feats[bi][c][hw0+r]
  {
    int c = t >> 1, half = t & 1;
    const float* src = feats + (size_t)(bi * CC + c) * HW + hw0 + half * 4;
    float4 a = *(const float4*)src;
    *(float4*)&zt[c][half * 4] = a;
  }
  if (t < ROWS) zzs[t] = out[ZZ_OFF + row0 + t];   // np-exact ||z||^2
  __syncthreads();

  // ---- fp32 GEMM, sequential-c FMA chain per (row,k) — bit-exact vs CPU sgemm
  const float* ct = out + CT_OFF;
  const int k0 = t * 4;
  float acc[ROWS][4];
  #pragma unroll
  for (int r = 0; r < ROWS; r++){ acc[r][0]=0.f; acc[r][1]=0.f; acc[r][2]=0.f; acc[r][3]=0.f; }

  const float* ctp = ct + k0;
  {
    float4 cv = *(const float4*)ctp;           // c = 0
    #pragma unroll 2
    for (int c = 0; c < CC - 1; c++){
      float4 cvn = *(const float4*)(ctp + (size_t)(c + 1) * KK);  // prefetch next
      float4 za = *(const float4*)&zt[c][0];
      float4 zb = *(const float4*)&zt[c][4];
      FMA_STEP(cv, za, zb)
      cv = cvn;
    }
    {
      float4 za = *(const float4*)&zt[CC-1][0];
      float4 zb = *(const float4*)&zt[CC-1][4];
      FMA_STEP(cv, za, zb)
    }
  }

  // ---- d = fl(fl(zz+ee) - 2*dot): matches numpy's elementwise roundings
  const float4 eev = *(const float4*)(out + EE_OFF + k0);
  #pragma unroll
  for (int r = 0; r < ROWS; r++){
    const float zr = zzs[r];
    acc[r][0] = __fadd_rn(__fadd_rn(zr, eev.x), -2.f * acc[r][0]);
    acc[r][1] = __fadd_rn(__fadd_rn(zr, eev.y), -2.f * acc[r][1]);
    acc[r][2] = __fadd_rn(__fadd_rn(zr, eev.z), -2.f * acc[r][2]);
    acc[r][3] = __fadd_rn(__fadd_rn(zr, eev.w), -2.f * acc[r][3]);
  }

  // ---- per-row fp32 min+argmin, lowest-k ties (= numpy first-index)
  #pragma unroll
  for (int r = 0; r < ROWS; r++){
    float v = acc[r][0]; int kk = k0;
    if (acc[r][1] < v){ v = acc[r][1]; kk = k0 + 1; }
    if (acc[r][2] < v){ v = acc[r][2]; kk = k0 + 2; }
    if (acc[r][3] < v){ v = acc[r][3]; kk = k0 + 3; }
    #pragma unroll
    for (int off = 32; off; off >>= 1){
      float v2 = __shfl_xor(v, off);
      int   k2 = __shfl_xor(kk, off);
      if (v2 < v || (v2 == v && k2 < kk)){ v = v2; kk = k2; }
    }
    if (lane == 0){ red_v[r][wv] = v; red_k[r][wv] = kk; }
  }
  __syncthreads();
  if (t < ROWS){
    float v = red_v[t][0]; int kk = red_k[t][0];
    #pragma unroll
    for (int j = 1; j < 8; j++){
      float v2 = red_v[t][j]; int k2 = red_k[t][j];
      if (v2 < v || (v2 == v && k2 < kk)){ v = v2; kk = k2; }
    }
    minv_s[t] = v; finidx[t] = kk;
  }
  __syncthreads();

  // ---- softmax(-|d|) = exp(min-d); row sums
  #pragma unroll
  for (int r = 0; r < ROWS; r++){
    float m = minv_s[r];
    float s = 0.f;
    #pragma unroll
    for (int i = 0; i < 4; i++){
      float e = __expf(m - acc[r][i]);
      acc[r][i] = e; s += e;
    }
    #pragma unroll
    for (int off = 32; off; off >>= 1) s += __shfl_xor(s, off);
    if (lane == 0) red_s[r][wv] = s;
  }
  __syncthreads();
  if (t < ROWS){
    float s = 0.f;
    #pragma unroll
    for (int j = 0; j < 8; j++) s += red_s[t][j];
    sum_s[t] = s;
  }
  __syncthreads();

  // ---- idx output (as float)
  if (t < ROWS) out[IDX_OFF + row0 + t] = (float)finidx[t];

  // ---- probs output: out[bi][k0+i][hw0+r]
  float inv[ROWS];
  #pragma unroll
  for (int r = 0; r < ROWS; r++) inv[r] = 1.f / sum_s[r];
  #pragma unroll
  for (int i = 0; i < 4; i++){
    size_t base = (size_t)PROBS_OFF + (size_t)(bi * KK + k0 + i) * HW + hw0;
    #pragma unroll
    for (int r = 0; r < ROWS; r++){
      out[base + r] = acc[r][i] * inv[r];
    }
  }

  // ---- loss partial: sum (cb[idx]-z)^2, one atomic per block, pre-scaled
  {
    int r = wv;  // one wave per row
    const float* crow = cb + (size_t)finidx[r] * CC;
    float s = 0.f;
    #pragma unroll
    for (int i = 0; i < 4; i++){
      int c = lane + 64 * i;
      float d = crow[c] - zt[c][r];
      s += d * d;
    }
    #pragma unroll
    for (int off = 32; off; off >>= 1) s += __shfl_xor(s, off);
    if (lane == 0) lred[r] = s;
  }
  __syncthreads();
  if (t == 0){
    float s = 0.f;
    #pragma unroll
    for (int r = 0; r < ROWS; r++) s += lred[r];
    atomicAdd(out + LOSS_OFF, s * (1.25f / 16777216.f));
  }
}

// ---------------- z_q gather: out[b][c][hw] = cb[idx[b,hw]][c] (bit-exact copy) ----------------
__global__ void k_zq(const float* __restrict__ cb, float* __restrict__ out){
  const int f4 = blockIdx.x * 256 + threadIdx.x;  // 16384 blocks
  const int f = f4 * 4;
  const int b = f >> 20;
  const int rem = f & 1048575;
  const int c = rem >> 12;
  const int hw = rem & 4095;
  const int n = b * HW + hw;
  const float* idxf = out + IDX_OFF;
  float4 iv = *(const float4*)(idxf + n);
  float4 o;
  o.x = cb[(size_t)((int)iv.x) * CC + c];
  o.y = cb[(size_t)((int)iv.y) * CC + c];
  o.z = cb[(size_t)((int)iv.z) * CC + c];
  o.w = cb[(size_t)((int)iv.w) * CC + c];
  *(float4*)(out + f) = o;
}

extern "C" void kernel_launch(void* const* d_in, const int* in_sizes, int n_in,
                              void* d_out, int out_size, void* d_ws, size_t ws_size,
                              hipStream_t stream){
  const float* feats = (const float*)d_in[0];
  const float* cb    = (const float*)d_in[1];
  float* out = (float*)d_out;

  (void)hipMemsetAsync(out + LOSS_OFF, 0, sizeof(float), stream);   // zero loss accumulator
  hipLaunchKernelGGL(k_prep, dim3(128),   dim3(256), 0, stream, cb, out);
  hipLaunchKernelGGL(k_ee,   dim3(8),     dim3(256), 0, stream, cb, out);
  hipLaunchKernelGGL(k_zz,   dim3(256),   dim3(256), 0, stream, feats, out);
  hipLaunchKernelGGL(k_main, dim3(8192),  dim3(512), 0, stream, feats, cb, out);
  hipLaunchKernelGGL(k_zq,   dim3(16384), dim3(256), 0, stream, cb, out);
}

// Round 5
// 1058.975 us; speedup vs baseline: 1.2029x; 1.2029x over previous
//
#include <hip/hip_runtime.h>

#define HW 4096
#define CC 256
#define KK 2048
#define BB 16
#define NN (BB*HW)          // 65536

// d_out layout (floats): [z_q 16777216][idx 65536][loss 1][probs 134217728]
#define ZQ_SZ   (BB*CC*HW)
#define IDX_OFF ZQ_SZ
#define LOSS_OFF (IDX_OFF + NN)
#define PROBS_OFF (LOSS_OFF + 1)

// scratch parked in z_q region (float offsets), overwritten by k_zq at the end
#define EH_OFF 0          // eh[K][C] bf16: 524288 shorts = 262144 floats
#define EL_OFF 262144     // el[K][C] bf16
#define EE_OFF 524288     // ee_np[K] f32
#define ZZ_OFF 589824     // zz_np[N] f32

#define TAU 1.5e-4f
#define CAND_CAP 6144

typedef short bf16x8 __attribute__((ext_vector_type(8)));
typedef float f32x16 __attribute__((ext_vector_type(16)));

__device__ __forceinline__ unsigned short bf16rn(float x){
  unsigned u = __float_as_uint(x);
  return (unsigned short)((u + 0x7fffu + ((u >> 16) & 1u)) >> 16);
}

// ---- numpy pairwise sum-of-squares over 256 elems (PW_BLOCKSIZE=128) ----
template<int STRIDE>
__device__ __forceinline__ float np_sumsq256(const float* __restrict__ a){
  float res0 = 0.f, res1 = 0.f;
  #pragma unroll
  for (int h = 0; h < 2; h++){
    const float* p = a + (size_t)h * 128 * STRIDE;
    float r[8];
    #pragma unroll
    for (int j = 0; j < 8; j++){ float x = p[(size_t)j * STRIDE]; r[j] = __fmul_rn(x, x); }
    for (int i = 8; i < 128; i += 8){
      #pragma unroll
      for (int j = 0; j < 8; j++){
        float x = p[(size_t)(i + j) * STRIDE];
        r[j] = __fadd_rn(r[j], __fmul_rn(x, x));
      }
    }
    float s = __fadd_rn(__fadd_rn(__fadd_rn(r[0], r[1]), __fadd_rn(r[2], r[3])),
                        __fadd_rn(__fadd_rn(r[4], r[5]), __fadd_rn(r[6], r[7])));
    if (h == 0) res0 = s; else res1 = s;
  }
  return __fadd_rn(res0, res1);
}

// ---------------- prep: bf16 split of codebook + np-exact ee ----------------
__global__ void k_prep2(const float* __restrict__ cb, float* __restrict__ out){
  const int k = blockIdx.x * 256 + threadIdx.x;   // 8 blocks -> 2048
  unsigned short* eh = (unsigned short*)(out + EH_OFF);
  unsigned short* el = (unsigned short*)(out + EL_OFF);
  const float* row = cb + (size_t)k * CC;
  for (int c = 0; c < CC; c++){
    float e = row[c];
    unsigned u = __float_as_uint(e);
    eh[k * CC + c] = (unsigned short)(u >> 16);
    float r = e - __uint_as_float(u & 0xffff0000u);
    el[k * CC + c] = bf16rn(r);
  }
  out[EE_OFF + k] = np_sumsq256<1>(row);
}

// ---------------- zz[n] = np-pairwise sum_c feats^2 ----------------
__global__ void k_zz(const float* __restrict__ feats, float* __restrict__ out){
  const int n = blockIdx.x * 256 + threadIdx.x;   // 256 blocks
  const int b = n >> 12, hw = n & 4095;
  out[ZZ_OFF + n] = np_sumsq256<HW>(feats + (size_t)b * CC * HW + hw);
}

// ---------------- main MFMA kernel ----------------
// block = 256 rows x 2048 codes; 8 waves x 32 rows; mfma_f32_32x32x16_bf16
__global__ __launch_bounds__(512, 2)
void k_mfma(const float* __restrict__ feats, const float* __restrict__ cb,
            float* __restrict__ out){
  __shared__ __align__(16) unsigned char lds_e[32768];   // [hl 16KB][code 512B][c]
  __shared__ float ee_lds[KK];
  __shared__ unsigned long long rowkey[256];
  __shared__ int cand[CAND_CAP];
  __shared__ int cand_n;
  __shared__ float lsum;

  const int t = threadIdx.x;
  const int w = t >> 6, l = t & 63;
  const int blk = blockIdx.x;            // 256
  const int n0 = blk * 256;
  const int bi = n0 >> 12;
  const int hw0 = n0 & 4095;
  const int rowl = l & 31;
  const int grp = l >> 5;                // c-subgroup for A/B frags
  const int code_l = l & 31;
  const int myhw = hw0 + w * 32 + rowl;

  for (int i = t; i < KK; i += 512) ee_lds[i] = out[EE_OFF + i];
  if (t < 256) rowkey[t] = ~0ull;
  if (t == 0){ cand_n = 0; lsum = 0.f; }

  // ---- A fragments (zh, zl) for this wave's 32 rows, resident in VGPRs
  bf16x8 ah[16], al[16];
  {
    const float* zb = feats + (size_t)bi * CC * HW + myhw;
    #pragma unroll
    for (int cs = 0; cs < 16; ++cs){
      #pragma unroll
      for (int j = 0; j < 8; ++j){
        int c = cs * 16 + grp * 8 + j;
        float z = zb[(size_t)c * HW];
        unsigned u = __float_as_uint(z);
        ah[cs][j] = (short)(u >> 16);
        float r = z - __uint_as_float(u & 0xffff0000u);
        al[cs][j] = (short)bf16rn(r);
      }
    }
  }

  const unsigned short* ehg = (const unsigned short*)(out + EH_OFF);
  const unsigned short* elg = (const unsigned short*)(out + EL_OFF);

  // staging decode (thread t, issue i): lds byte p=(i*512+t)*16
  int s_hl[4], s_code[4], s_csrc[4];
  #pragma unroll
  for (int i = 0; i < 4; ++i){
    int p = (i * 512 + t) * 16;
    s_hl[i] = p >> 14;
    s_code[i] = (p >> 9) & 31;
    s_csrc[i] = ((p >> 4) & 31) ^ (s_code[i] & 7);   // XOR-swizzle (G4)
  }
  float4 stg[4];

#define VLOAD(KT) { \
    _Pragma("unroll") \
    for (int i = 0; i < 4; ++i){ \
      const unsigned short* src = (s_hl[i] ? elg : ehg) + \
        ((size_t)((KT) * 32 + s_code[i]) * CC + s_csrc[i] * 8); \
      stg[i] = *(const float4*)src; \
    } }

#define DSWRITE() { \
    _Pragma("unroll") \
    for (int i = 0; i < 4; ++i) *(float4*)(lds_e + (i * 512 + t) * 16) = stg[i]; }

#define COMPUTE(ACC) { \
    _Pragma("unroll") \
    for (int ii = 0; ii < 16; ++ii) ACC[ii] = 0.f; \
    _Pragma("unroll") \
    for (int cs = 0; cs < 16; ++cs){ \
      int sw = (cs * 32 + grp * 16) ^ ((code_l & 7) << 4); \
      const unsigned char* bp = lds_e + code_l * 512 + sw; \
      bf16x8 bh = *(const bf16x8*)(bp); \
      bf16x8 bl = *(const bf16x8*)(bp + 16384); \
      ACC = __builtin_amdgcn_mfma_f32_32x32x16_bf16(ah[cs], bh, ACC, 0, 0, 0); \
      ACC = __builtin_amdgcn_mfma_f32_32x32x16_bf16(ah[cs], bl, ACC, 0, 0, 0); \
      ACC = __builtin_amdgcn_mfma_f32_32x32x16_bf16(al[cs], bh, ACC, 0, 0, 0); \
      ACC = __builtin_amdgcn_mfma_f32_32x32x16_bf16(al[cs], bl, ACC, 0, 0, 0); \
    } }

  // ---- pass 1: online min & softmax denominator
  float m_[16], sum_[16];
  #pragma unroll
  for (int r = 0; r < 16; ++r){ m_[r] = 3e38f; sum_[r] = 0.f; }

  VLOAD(0);
  for (int kt = 0; kt < 64; ++kt){
    __syncthreads();
    DSWRITE();
    __syncthreads();
    if (kt < 63) VLOAD(kt + 1);
    float eev = ee_lds[kt * 32 + code_l];
    f32x16 acc;
    COMPUTE(acc);
    #pragma unroll
    for (int r = 0; r < 16; ++r){
      float s = eev - 2.f * acc[r];
      float mn = fminf(m_[r], s);
      sum_[r] = sum_[r] * __expf(mn - m_[r]) + __expf(mn - s);
      m_[r] = mn;
    }
  }

  // merge stats across the 32 lanes sharing each row-set (butterfly keeps result everywhere)
  #pragma unroll
  for (int r = 0; r < 16; ++r){
    float m = m_[r], ss = sum_[r];
    #pragma unroll
    for (int off = 1; off < 32; off <<= 1){
      float m2 = __shfl_xor(m, off);
      float s2 = __shfl_xor(ss, off);
      float mn = fminf(m, m2);
      ss = ss * __expf(mn - m) + s2 * __expf(mn - m2);
      m = mn;
    }
    m_[r] = m; sum_[r] = 1.f / ss;   // sum_ now holds inv_sum
  }

  // ---- pass 2: probs + candidate collection
  VLOAD(0);
  for (int kt = 0; kt < 64; ++kt){
    __syncthreads();
    DSWRITE();
    __syncthreads();
    if (kt < 63) VLOAD(kt + 1);
    float eev = ee_lds[kt * 32 + code_l];
    f32x16 acc;
    COMPUTE(acc);
    int codeg = kt * 32 + code_l;
    size_t pbase = (size_t)PROBS_OFF + (size_t)(bi * KK + codeg) * HW;
    #pragma unroll
    for (int r = 0; r < 16; ++r){
      float s = eev - 2.f * acc[r];
      float p = __expf(m_[r] - s) * sum_[r];
      int rloc = w * 32 + (r & 3) + 8 * (r >> 2) + 4 * grp;
      out[pbase + hw0 + rloc] = p;
      if (s <= m_[r] + TAU){
        int slot = atomicAdd(&cand_n, 1);
        if (slot < CAND_CAP) cand[slot] = (rloc << 16) | codeg;
      }
    }
  }
  __syncthreads();

  // ---- bit-exact rescore of candidates (numpy fp32 chain), first-min wins
  int nc = cand_n; if (nc > CAND_CAP) nc = CAND_CAP;
  for (int i = t; i < nc; i += 512){
    int rc = cand[i];
    int rl = rc >> 16, code = rc & 0xffff;
    int n = n0 + rl;
    const float* zp = feats + (size_t)(n >> 12) * CC * HW + (n & 4095);
    const float* ep = cb + (size_t)code * CC;
    float a = 0.f;
    #pragma unroll 8
    for (int c = 0; c < CC; ++c) a = __builtin_fmaf(zp[(size_t)c * HW], ep[c], a);
    float t1 = __fadd_rn(out[ZZ_OFF + n], ee_lds[code]);
    float d = __fadd_rn(t1, -2.f * a);
    unsigned long long key = ((unsigned long long)__float_as_uint(d) << 32) | (unsigned)code;
    atomicMin(&rowkey[rl], key);
  }
  __syncthreads();

  if (t < 256) out[IDX_OFF + n0 + t] = (float)(int)(rowkey[t] & 0xffffffffu);

  // ---- loss: sum (cb[idx]-z)^2 over block rows
  {
    int rl = w * 32 + (l & 31);
    int code = (int)(rowkey[rl] & 0xffffffffu);
    const float* ep = cb + (size_t)code * CC;
    int n = n0 + rl;
    const float* zp = feats + (size_t)(n >> 12) * CC * HW + (n & 4095);
    float s = 0.f;
    int c0 = grp * 128;
    for (int c = c0; c < c0 + 128; ++c){
      float dz = ep[c] - zp[(size_t)c * HW];
      s = __builtin_fmaf(dz, dz, s);
    }
    s += __shfl_xor(s, 32);
    if (grp == 0) atomicAdd(&lsum, s);
  }
  __syncthreads();
  if (t == 0) atomicAdd(out + LOSS_OFF, lsum * (1.25f / 16777216.f));
}

// ---------------- z_q gather (bit-exact copy; overwrites scratch) ----------------
__global__ void k_zq(const float* __restrict__ cb, float* __restrict__ out){
  const int f4 = blockIdx.x * 256 + threadIdx.x;  // 16384 blocks
  const int f = f4 * 4;
  const int b = f >> 20;
  const int rem = f & 1048575;
  const int c = rem >> 12;
  const int hw = rem & 4095;
  const int n = b * HW + hw;
  const float* idxf = out + IDX_OFF;
  float4 iv = *(const float4*)(idxf + n);
  float4 o;
  o.x = cb[(size_t)((int)iv.x) * CC + c];
  o.y = cb[(size_t)((int)iv.y) * CC + c];
  o.z = cb[(size_t)((int)iv.z) * CC + c];
  o.w = cb[(size_t)((int)iv.w) * CC + c];
  *(float4*)(out + f) = o;
}

extern "C" void kernel_launch(void* const* d_in, const int* in_sizes, int n_in,
                              void* d_out, int out_size, void* d_ws, size_t ws_size,
                              hipStream_t stream){
  const float* feats = (const float*)d_in[0];
  const float* cb    = (const float*)d_in[1];
  float* out = (float*)d_out;

  (void)hipMemsetAsync(out + LOSS_OFF, 0, sizeof(float), stream);
  hipLaunchKernelGGL(k_prep2, dim3(8),     dim3(256), 0, stream, cb, out);
  hipLaunchKernelGGL(k_zz,    dim3(256),   dim3(256), 0, stream, feats, out);
  hipLaunchKernelGGL(k_mfma,  dim3(256),   dim3(512), 0, stream, feats, cb, out);
  hipLaunchKernelGGL(k_zq,    dim3(16384), dim3(256), 0, stream, cb, out);
}

// Round 6
// 738.781 us; speedup vs baseline: 1.7243x; 1.4334x over previous
//
#include <hip/hip_runtime.h>

#define HW 4096
#define CC 256
#define KK 2048
#define BB 16
#define NN (BB*HW)          // 65536

// d_out layout (floats): [z_q 16777216][idx 65536][loss 1][probs 134217728]
#define ZQ_SZ   (BB*CC*HW)
#define IDX_OFF ZQ_SZ
#define LOSS_OFF (IDX_OFF + NN)
#define PROBS_OFF (LOSS_OFF + 1)

// scratch parked in z_q region (float offsets), overwritten by k_zq at the end
#define EH_OFF 0          // eh[K][C] bf16
#define EL_OFF 262144     // el[K][C] bf16
#define EE_OFF 524288     // ee_np[K] f32
#define ZZ_OFF 589824     // zz_np[N] f32

#define TAU 1.5e-4f
#define CAND_CAP 6144
#define KTC 32            // codes per k-tile
#define KT_N 64           // tiles

typedef short bf16x8 __attribute__((ext_vector_type(8)));
typedef float f32x16 __attribute__((ext_vector_type(16)));

__device__ __forceinline__ unsigned short bf16rn(float x){
  unsigned u = __float_as_uint(x);
  return (unsigned short)((u + 0x7fffu + ((u >> 16) & 1u)) >> 16);
}

// ---- numpy pairwise sum-of-squares over 256 elems (PW_BLOCKSIZE=128) ----
template<int STRIDE>
__device__ __forceinline__ float np_sumsq256(const float* __restrict__ a){
  float res0 = 0.f, res1 = 0.f;
  #pragma unroll
  for (int h = 0; h < 2; h++){
    const float* p = a + (size_t)h * 128 * STRIDE;
    float r[8];
    #pragma unroll
    for (int j = 0; j < 8; j++){ float x = p[(size_t)j * STRIDE]; r[j] = __fmul_rn(x, x); }
    for (int i = 8; i < 128; i += 8){
      #pragma unroll
      for (int j = 0; j < 8; j++){
        float x = p[(size_t)(i + j) * STRIDE];
        r[j] = __fadd_rn(r[j], __fmul_rn(x, x));
      }
    }
    float s = __fadd_rn(__fadd_rn(__fadd_rn(r[0], r[1]), __fadd_rn(r[2], r[3])),
                        __fadd_rn(__fadd_rn(r[4], r[5]), __fadd_rn(r[6], r[7])));
    if (h == 0) res0 = s; else res1 = s;
  }
  return __fadd_rn(res0, res1);
}

// ---------------- prep: rn bf16 split of codebook + np-exact ee ----------------
__global__ void k_prep2(const float* __restrict__ cb, float* __restrict__ out){
  const int k = blockIdx.x * 256 + threadIdx.x;   // 8 blocks
  unsigned short* eh = (unsigned short*)(out + EH_OFF);
  unsigned short* el = (unsigned short*)(out + EL_OFF);
  const float* row = cb + (size_t)k * CC;
  for (int c = 0; c < CC; c++){
    float e = row[c];
    unsigned short h = bf16rn(e);
    eh[k * CC + c] = h;
    float hf = __uint_as_float((unsigned)h << 16);
    el[k * CC + c] = bf16rn(e - hf);
  }
  out[EE_OFF + k] = np_sumsq256<1>(row);
}

// ---------------- zz[n] = np-pairwise sum_c feats^2 ----------------
__global__ void k_zz(const float* __restrict__ feats, float* __restrict__ out){
  const int n = blockIdx.x * 256 + threadIdx.x;   // 256 blocks
  const int b = n >> 12, hw = n & 4095;
  out[ZZ_OFF + n] = np_sumsq256<HW>(feats + (size_t)b * CC * HW + hw);
}

// ---------------- main MFMA kernel: 256 rows x 2048 codes per block ----------------
__global__ __launch_bounds__(512, 2)
void k_mfma(const float* __restrict__ feats, const float* __restrict__ cb,
            float* __restrict__ out){
  __shared__ __align__(16) unsigned char lds_e[32768];   // [hl 16KB][code 512B][c]
  __shared__ float ee_lds[KK];
  __shared__ float pbuf[8448];                            // 8 waves x 32x33 f32
  __shared__ unsigned long long rowkey[256];
  __shared__ int cand[CAND_CAP];
  __shared__ int cand_n;
  __shared__ float lsum;

  const int t = threadIdx.x;
  const int w = t >> 6, l = t & 63;
  const int blk = blockIdx.x;            // 256
  const int n0 = blk * 256;
  const int bi = n0 >> 12;
  const int hw0 = n0 & 4095;
  const int grp = l >> 5;
  const int code_l = l & 31;
  const int myhw = hw0 + w * 32 + (l & 31);
  const int wb = w * 1056;

  for (int i = t; i < KK; i += 512) ee_lds[i] = out[EE_OFF + i];
  if (t < 256) rowkey[t] = ~0ull;
  if (t == 0){ cand_n = 0; lsum = 0.f; }

  // ---- A fragments (zh, zl rn-split) resident in VGPRs
  bf16x8 ah[16], al[16];
  {
    const float* zb = feats + (size_t)bi * CC * HW + myhw;
    #pragma unroll
    for (int cs = 0; cs < 16; ++cs){
      #pragma unroll
      for (int j = 0; j < 8; ++j){
        int c = cs * 16 + grp * 8 + j;
        float z = zb[(size_t)c * HW];
        unsigned short h = bf16rn(z);
        ah[cs][j] = (short)h;
        float hf = __uint_as_float((unsigned)h << 16);
        al[cs][j] = (short)bf16rn(z - hf);
      }
    }
  }

  const unsigned short* ehg = (const unsigned short*)(out + EH_OFF);
  const unsigned short* elg = (const unsigned short*)(out + EL_OFF);
  float4 stg[4];

#define VLOAD(KT) { \
    _Pragma("unroll") \
    for (int i_ = 0; i_ < 4; ++i_){ \
      int p_ = (i_ * 512 + t) * 16; \
      int hl_ = p_ >> 14; \
      int q_ = p_ & 16383; \
      int cd_ = q_ >> 9; \
      int g_ = (q_ >> 4) & 31; \
      const unsigned short* src_ = (hl_ ? elg : ehg) + \
        ((size_t)((KT) * KTC + cd_) * CC + (size_t)((g_ ^ (cd_ & 7)) * 8)); \
      stg[i_] = *(const float4*)src_; \
    } }

#define DSWRITE() { \
    _Pragma("unroll") \
    for (int i_ = 0; i_ < 4; ++i_) *(float4*)(lds_e + (i_ * 512 + t) * 16) = stg[i_]; }

  // 3-product split GEMM, two alternating accumulators (dep-distance 2)
#define COMPUTE() \
    _Pragma("unroll") \
    for (int ii = 0; ii < 16; ++ii){ accA[ii] = 0.f; accB[ii] = 0.f; } \
    _Pragma("unroll") \
    for (int cs = 0; cs < 16; ++cs){ \
      int sw_ = (cs * 32 + grp * 16) ^ ((code_l & 7) << 4); \
      const unsigned char* bp_ = lds_e + code_l * 512 + sw_; \
      bf16x8 bh_ = *(const bf16x8*)(bp_); \
      bf16x8 bl_ = *(const bf16x8*)(bp_ + 16384); \
      if (cs & 1){ \
        accB = __builtin_amdgcn_mfma_f32_32x32x16_bf16(ah[cs], bh_, accB, 0, 0, 0); \
        accB = __builtin_amdgcn_mfma_f32_32x32x16_bf16(ah[cs], bl_, accB, 0, 0, 0); \
        accB = __builtin_amdgcn_mfma_f32_32x32x16_bf16(al[cs], bh_, accB, 0, 0, 0); \
      } else { \
        accA = __builtin_amdgcn_mfma_f32_32x32x16_bf16(ah[cs], bh_, accA, 0, 0, 0); \
        accA = __builtin_amdgcn_mfma_f32_32x32x16_bf16(ah[cs], bl_, accA, 0, 0, 0); \
        accA = __builtin_amdgcn_mfma_f32_32x32x16_bf16(al[cs], bh_, accA, 0, 0, 0); \
      } \
    }

  f32x16 accA, accB;
  float m_[16], sum_[16];
  #pragma unroll
  for (int r = 0; r < 16; ++r){ m_[r] = 3e38f; sum_[r] = 0.f; }

  // ================= pass 1: min + shift-free softmax denominator =================
  VLOAD(0);
  for (int kt = 0; kt < KT_N; ++kt){
    __syncthreads();
    DSWRITE();
    __syncthreads();
    if (kt < KT_N - 1) VLOAD(kt + 1);
    COMPUTE();
    float eev = ee_lds[kt * KTC + code_l];
    #pragma unroll
    for (int r = 0; r < 16; ++r){
      float s = eev - 2.f * (accA[r] + accB[r]);
      m_[r] = fminf(m_[r], s);
      sum_[r] += __expf(-s);       // s in [-1,1]: no overflow, no shift needed
    }
  }

  // merge stats across the 32 code-lanes (butterfly; stays within grp half)
  #pragma unroll
  for (int r = 0; r < 16; ++r){
    float m = m_[r], ss = sum_[r];
    #pragma unroll
    for (int off = 1; off < 32; off <<= 1){
      m = fminf(m, __shfl_xor(m, off));
      ss += __shfl_xor(ss, off);
    }
    m_[r] = m; sum_[r] = 1.f / ss;   // sum_ now inv_sum
  }

  // ================= pass 2: probs (coalesced via wave-local transpose) + candidates =================
  VLOAD(0);
  for (int kt = 0; kt < KT_N; ++kt){
    __syncthreads();
    DSWRITE();
    __syncthreads();
    if (kt < KT_N - 1) VLOAD(kt + 1);
    COMPUTE();
    float eev = ee_lds[kt * KTC + code_l];
    #pragma unroll
    for (int r = 0; r < 16; ++r){
      float s = eev - 2.f * (accA[r] + accB[r]);
      float p = __expf(-s) * sum_[r];
      int rloc = (r & 3) + 8 * (r >> 2) + 4 * grp;       // local row 0..31
      pbuf[wb + code_l * 33 + rloc] = p;
      if (s <= m_[r] + TAU){
        int slot = atomicAdd(&cand_n, 1);
        if (slot < CAND_CAP) cand[slot] = ((w * 32 + rloc) << 16) | (kt * KTC + code_l);
      }
    }
    // wave-local transpose store: two 128B segments per instruction
    const int row = l & 31, hi = l >> 5;
    #pragma unroll
    for (int i = 0; i < 16; ++i){
      int codel = 2 * i + hi;
      float pv = pbuf[wb + codel * 33 + row];
      out[(size_t)PROBS_OFF + (size_t)(bi * KK + kt * KTC + codel) * HW + hw0 + w * 32 + row] = pv;
    }
  }
  __syncthreads();

  // ---- bit-exact rescore of candidates (numpy fp32 chain), first-min wins
  int nc = cand_n; if (nc > CAND_CAP) nc = CAND_CAP;
  for (int i = t; i < nc; i += 512){
    int rc = cand[i];
    int rl = rc >> 16, code = rc & 0xffff;
    int n = n0 + rl;
    const float* zp = feats + (size_t)(n >> 12) * CC * HW + (n & 4095);
    const float* ep = cb + (size_t)code * CC;
    float a = 0.f;
    #pragma unroll 8
    for (int c = 0; c < CC; ++c) a = __builtin_fmaf(zp[(size_t)c * HW], ep[c], a);
    float t1 = __fadd_rn(out[ZZ_OFF + n], ee_lds[code]);
    float d = __fadd_rn(t1, -2.f * a);
    unsigned long long key = ((unsigned long long)__float_as_uint(d) << 32) | (unsigned)code;
    atomicMin(&rowkey[rl], key);
  }
  __syncthreads();

  if (t < 256) out[IDX_OFF + n0 + t] = (float)(int)(rowkey[t] & 0xffffffffu);

  // ---- loss: sum (cb[idx]-z)^2 over block rows
  {
    int rl = w * 32 + (l & 31);
    int code = (int)(rowkey[rl] & 0xffffffffu);
    const float* ep = cb + (size_t)code * CC;
    int n = n0 + rl;
    const float* zp = feats + (size_t)(n >> 12) * CC * HW + (n & 4095);
    float s = 0.f;
    int c0 = grp * 128;
    for (int c = c0; c < c0 + 128; ++c){
      float dz = ep[c] - zp[(size_t)c * HW];
      s = __builtin_fmaf(dz, dz, s);
    }
    s += __shfl_xor(s, 32);
    if (grp == 0) atomicAdd(&lsum, s);
  }
  __syncthreads();
  if (t == 0) atomicAdd(out + LOSS_OFF, lsum * (1.25f / 16777216.f));
}

// ---------------- z_q gather (bit-exact copy; overwrites scratch) ----------------
__global__ void k_zq(const float* __restrict__ cb, float* __restrict__ out){
  const int f4 = blockIdx.x * 256 + threadIdx.x;  // 16384 blocks
  const int f = f4 * 4;
  const int b = f >> 20;
  const int rem = f & 1048575;
  const int c = rem >> 12;
  const int hw = rem & 4095;
  const int n = b * HW + hw;
  const float* idxf = out + IDX_OFF;
  float4 iv = *(const float4*)(idxf + n);
  float4 o;
  o.x = cb[(size_t)((int)iv.x) * CC + c];
  o.y = cb[(size_t)((int)iv.y) * CC + c];
  o.z = cb[(size_t)((int)iv.z) * CC + c];
  o.w = cb[(size_t)((int)iv.w) * CC + c];
  *(float4*)(out + f) = o;
}

extern "C" void kernel_launch(void* const* d_in, const int* in_sizes, int n_in,
                              void* d_out, int out_size, void* d_ws, size_t ws_size,
                              hipStream_t stream){
  const float* feats = (const float*)d_in[0];
  const float* cb    = (const float*)d_in[1];
  float* out = (float*)d_out;

  (void)hipMemsetAsync(out + LOSS_OFF, 0, sizeof(float), stream);
  hipLaunchKernelGGL(k_prep2, dim3(8),     dim3(256), 0, stream, cb, out);
  hipLaunchKernelGGL(k_zz,    dim3(256),   dim3(256), 0, stream, feats, out);
  hipLaunchKernelGGL(k_mfma,  dim3(256),   dim3(512), 0, stream, feats, cb, out);
  hipLaunchKernelGGL(k_zq,    dim3(16384), dim3(256), 0, stream, cb, out);
}

// Round 7
// 500.799 us; speedup vs baseline: 2.5437x; 1.4752x over previous
//
#include <hip/hip_runtime.h>

#define HW 4096
#define CC 256
#define KK 2048
#define BB 16
#define NN (BB*HW)          // 65536

// d_out layout (floats): [z_q 16777216][idx 65536][loss 1][probs 134217728]
#define ZQ_SZ   (BB*CC*HW)
#define IDX_OFF ZQ_SZ
#define LOSS_OFF (IDX_OFF + NN)
#define PROBS_OFF (LOSS_OFF + 1)

// scratch parked in z_q region (float offsets), overwritten by k_zq at the end
#define EH_OFF 0          // eh[K][C] bf16 (rn) = 262144 floats
#define EE_OFF 262144     // ee_np[K] f32
#define ZZ_OFF 264192     // zz_np[N] f32

#define TAU 0.01f
#define CAND_CAP 2048
#define KTC 64            // codes per k-tile
#define KT_N 32           // tiles

typedef short bf16x8 __attribute__((ext_vector_type(8)));
typedef float f32x16 __attribute__((ext_vector_type(16)));

__device__ __forceinline__ unsigned short bf16rn(float x){
  unsigned u = __float_as_uint(x);
  return (unsigned short)((u + 0x7fffu + ((u >> 16) & 1u)) >> 16);
}

// ---- numpy pairwise sum-of-squares over 256 elems (PW_BLOCKSIZE=128) ----
template<int STRIDE>
__device__ __forceinline__ float np_sumsq256(const float* __restrict__ a){
  float res0 = 0.f, res1 = 0.f;
  #pragma unroll
  for (int h = 0; h < 2; h++){
    const float* p = a + (size_t)h * 128 * STRIDE;
    float r[8];
    #pragma unroll
    for (int j = 0; j < 8; j++){ float x = p[(size_t)j * STRIDE]; r[j] = __fmul_rn(x, x); }
    for (int i = 8; i < 128; i += 8){
      #pragma unroll
      for (int j = 0; j < 8; j++){
        float x = p[(size_t)(i + j) * STRIDE];
        r[j] = __fadd_rn(r[j], __fmul_rn(x, x));
      }
    }
    float s = __fadd_rn(__fadd_rn(__fadd_rn(r[0], r[1]), __fadd_rn(r[2], r[3])),
                        __fadd_rn(__fadd_rn(r[4], r[5]), __fadd_rn(r[6], r[7])));
    if (h == 0) res0 = s; else res1 = s;
  }
  return __fadd_rn(res0, res1);
}

// ---------------- prep: bf16(rn) codebook + np-exact ee ----------------
__global__ void k_prep2(const float* __restrict__ cb, float* __restrict__ out){
  const int k = blockIdx.x * 256 + threadIdx.x;   // 8 blocks
  unsigned short* eh = (unsigned short*)(out + EH_OFF);
  const float* row = cb + (size_t)k * CC;
  for (int c = 0; c < CC; c++) eh[k * CC + c] = bf16rn(row[c]);
  out[EE_OFF + k] = np_sumsq256<1>(row);
}

// ---------------- zz[n] = np-pairwise sum_c feats^2 ----------------
__global__ void k_zz(const float* __restrict__ feats, float* __restrict__ out){
  const int n = blockIdx.x * 256 + threadIdx.x;   // 256 blocks
  const int b = n >> 12, hw = n & 4095;
  out[ZZ_OFF + n] = np_sumsq256<HW>(feats + (size_t)b * CC * HW + hw);
}

// ---------------- main MFMA kernel: 256 rows x 2048 codes per block ----------------
// lds_e layout: [cs 16][grp 2][code 64][16B]  -> conflict-free ds_read_b128
__global__ __launch_bounds__(512, 2)
void k_mfma(const float* __restrict__ feats, const float* __restrict__ cb,
            float* __restrict__ out){
  __shared__ __align__(16) unsigned char lds_e[32768];
  __shared__ float ee_lds[KK];
  __shared__ float pbuf[8448];                     // 8 waves x 32x33 f32
  __shared__ unsigned long long rowkey[256];
  __shared__ int cand[CAND_CAP];
  __shared__ int cand_n;
  __shared__ float lsum;

  const int t = threadIdx.x;
  const int w = t >> 6, l = t & 63;
  const int blk = blockIdx.x;            // 256
  const int n0 = blk * 256;
  const int bi = n0 >> 12;
  const int hw0 = n0 & 4095;
  const int grp = l >> 5;
  const int code_l = l & 31;
  const int myhw = hw0 + w * 32 + (l & 31);
  const int wb = w * 1056;

  for (int i = t; i < KK; i += 512) ee_lds[i] = out[EE_OFF + i];
  if (t < 256) rowkey[t] = ~0ull;
  if (t == 0){ cand_n = 0; lsum = 0.f; }

  // ---- A fragments (bf16 rn) resident in VGPRs
  bf16x8 ah[16];
  {
    const float* zb = feats + (size_t)bi * CC * HW + myhw;
    #pragma unroll
    for (int cs = 0; cs < 16; ++cs){
      #pragma unroll
      for (int j = 0; j < 8; ++j){
        int c = cs * 16 + grp * 8 + j;
        ah[cs][j] = (short)bf16rn(zb[(size_t)c * HW]);
      }
    }
  }

  const unsigned short* ehg = (const unsigned short*)(out + EH_OFF);
  float4 stg[4];

// staging: idx16 = i*512+t; code=idx16&63; grp_=(idx16>>6)&1; cs_=idx16>>7
#define VLOAD(KT) { \
    _Pragma("unroll") \
    for (int i_ = 0; i_ < 4; ++i_){ \
      int ix_ = i_ * 512 + t; \
      int cd_ = ix_ & 63; \
      int g_  = (ix_ >> 6) & 1; \
      int cs_ = ix_ >> 7; \
      stg[i_] = *(const float4*)(ehg + (size_t)((KT) * KTC + cd_) * CC + cs_ * 16 + g_ * 8); \
    } }

#define DSWRITE() { \
    _Pragma("unroll") \
    for (int i_ = 0; i_ < 4; ++i_) *(float4*)(lds_e + (i_ * 512 + t) * 16) = stg[i_]; }

  // single bf16 product; 4 independent MFMA chains (2 per code-frag)
#define COMPUTE() \
    _Pragma("unroll") \
    for (int ii = 0; ii < 16; ++ii){ accA[ii] = 0.f; accB[ii] = 0.f; accC[ii] = 0.f; accD[ii] = 0.f; } \
    _Pragma("unroll") \
    for (int cs = 0; cs < 16; ++cs){ \
      const unsigned char* bp_ = lds_e + (size_t)(cs * 2 + grp) * 1024 + code_l * 16; \
      bf16x8 b0_ = *(const bf16x8*)(bp_); \
      bf16x8 b1_ = *(const bf16x8*)(bp_ + 512); \
      if (cs & 1){ \
        accB = __builtin_amdgcn_mfma_f32_32x32x16_bf16(ah[cs], b0_, accB, 0, 0, 0); \
        accD = __builtin_amdgcn_mfma_f32_32x32x16_bf16(ah[cs], b1_, accD, 0, 0, 0); \
      } else { \
        accA = __builtin_amdgcn_mfma_f32_32x32x16_bf16(ah[cs], b0_, accA, 0, 0, 0); \
        accC = __builtin_amdgcn_mfma_f32_32x32x16_bf16(ah[cs], b1_, accC, 0, 0, 0); \
      } \
    }

  f32x16 accA, accB, accC, accD;
  float m_[16], sum_[16];
  #pragma unroll
  for (int r = 0; r < 16; ++r){ m_[r] = 3e38f; sum_[r] = 0.f; }

  // ================= pass 1: min + shift-free softmax denominator =================
  VLOAD(0);
  for (int kt = 0; kt < KT_N; ++kt){
    __syncthreads();
    DSWRITE();
    __syncthreads();
    if (kt < KT_N - 1) VLOAD(kt + 1);
    COMPUTE();
    float eev0 = ee_lds[kt * KTC + code_l];
    float eev1 = ee_lds[kt * KTC + 32 + code_l];
    #pragma unroll
    for (int r = 0; r < 16; ++r){
      float s0 = eev0 - 2.f * (accA[r] + accB[r]);
      float s1 = eev1 - 2.f * (accC[r] + accD[r]);
      m_[r] = fminf(m_[r], fminf(s0, s1));
      sum_[r] += __expf(-s0) + __expf(-s1);   // s in [-1,1]: no shift needed
    }
  }

  // merge across the 32 code-lanes (butterfly within each grp half)
  #pragma unroll
  for (int r = 0; r < 16; ++r){
    float m = m_[r], ss = sum_[r];
    #pragma unroll
    for (int off = 1; off < 32; off <<= 1){
      m = fminf(m, __shfl_xor(m, off));
      ss += __shfl_xor(ss, off);
    }
    m_[r] = m; sum_[r] = 1.f / ss;
  }

  // ================= pass 2: probs (transpose-coalesced) + candidates =================
  VLOAD(0);
  for (int kt = 0; kt < KT_N; ++kt){
    __syncthreads();
    DSWRITE();
    __syncthreads();
    if (kt < KT_N - 1) VLOAD(kt + 1);
    COMPUTE();
    float eev0 = ee_lds[kt * KTC + code_l];
    float eev1 = ee_lds[kt * KTC + 32 + code_l];
    const int row = l & 31, hi = l >> 5;
    #pragma unroll
    for (int cf = 0; cf < 2; ++cf){
      #pragma unroll
      for (int r = 0; r < 16; ++r){
        float a = cf ? (accC[r] + accD[r]) : (accA[r] + accB[r]);
        float s = (cf ? eev1 : eev0) - 2.f * a;
        float p = __expf(-s) * sum_[r];
        int rloc = (r & 3) + 8 * (r >> 2) + 4 * grp;
        pbuf[wb + code_l * 33 + rloc] = p;
        if (s <= m_[r] + TAU){
          int slot = atomicAdd(&cand_n, 1);
          if (slot < CAND_CAP) cand[slot] = ((w * 32 + rloc) << 16) | (kt * KTC + cf * 32 + code_l);
        }
      }
      // wave-local transpose store: two 128B segments per instruction
      #pragma unroll
      for (int i = 0; i < 16; ++i){
        int codel = 2 * i + hi;
        float pv = pbuf[wb + codel * 33 + row];
        out[(size_t)PROBS_OFF + (size_t)(bi * KK + kt * KTC + cf * 32 + codel) * HW + hw0 + w * 32 + row] = pv;
      }
    }
  }
  __syncthreads();

  // ---- bit-exact rescore of candidates (numpy fp32 chain), first-min wins
  int nc = cand_n; if (nc > CAND_CAP) nc = CAND_CAP;
  for (int i = t; i < nc; i += 512){
    int rc = cand[i];
    int rl = rc >> 16, code = rc & 0xffff;
    int n = n0 + rl;
    const float* zp = feats + (size_t)(n >> 12) * CC * HW + (n & 4095);
    const float* ep = cb + (size_t)code * CC;
    float a = 0.f;
    #pragma unroll 8
    for (int c = 0; c < CC; ++c) a = __builtin_fmaf(zp[(size_t)c * HW], ep[c], a);
    float t1 = __fadd_rn(out[ZZ_OFF + n], ee_lds[code]);
    float d = __fadd_rn(t1, -2.f * a);
    unsigned long long key = ((unsigned long long)__float_as_uint(d) << 32) | (unsigned)code;
    atomicMin(&rowkey[rl], key);
  }
  __syncthreads();

  if (t < 256) out[IDX_OFF + n0 + t] = (float)(int)(rowkey[t] & 0xffffffffu);

  // ---- loss: sum (cb[idx]-z)^2 over block rows
  {
    int rl = w * 32 + (l & 31);
    int code = (int)(rowkey[rl] & 0xffffffffu);
    const float* ep = cb + (size_t)code * CC;
    int n = n0 + rl;
    const float* zp = feats + (size_t)(n >> 12) * CC * HW + (n & 4095);
    float s = 0.f;
    int c0 = grp * 128;
    for (int c = c0; c < c0 + 128; ++c){
      float dz = ep[c] - zp[(size_t)c * HW];
      s = __builtin_fmaf(dz, dz, s);
    }
    s += __shfl_xor(s, 32);
    if (grp == 0) atomicAdd(&lsum, s);
  }
  __syncthreads();
  if (t == 0) atomicAdd(out + LOSS_OFF, lsum * (1.25f / 16777216.f));
}

// ---------------- z_q gather (bit-exact copy; overwrites scratch) ----------------
__global__ void k_zq(const float* __restrict__ cb, float* __restrict__ out){
  const int f4 = blockIdx.x * 256 + threadIdx.x;  // 16384 blocks
  const int f = f4 * 4;
  const int b = f >> 20;
  const int rem = f & 1048575;
  const int c = rem >> 12;
  const int hw = rem & 4095;
  const int n = b * HW + hw;
  const float* idxf = out + IDX_OFF;
  float4 iv = *(const float4*)(idxf + n);
  float4 o;
  o.x = cb[(size_t)((int)iv.x) * CC + c];
  o.y = cb[(size_t)((int)iv.y) * CC + c];
  o.z = cb[(size_t)((int)iv.z) * CC + c];
  o.w = cb[(size_t)((int)iv.w) * CC + c];
  *(float4*)(out + f) = o;
}

extern "C" void kernel_launch(void* const* d_in, const int* in_sizes, int n_in,
                              void* d_out, int out_size, void* d_ws, size_t ws_size,
                              hipStream_t stream){
  const float* feats = (const float*)d_in[0];
  const float* cb    = (const float*)d_in[1];
  float* out = (float*)d_out;

  (void)hipMemsetAsync(out + LOSS_OFF, 0, sizeof(float), stream);
  hipLaunchKernelGGL(k_prep2, dim3(8),     dim3(256), 0, stream, cb, out);
  hipLaunchKernelGGL(k_zz,    dim3(256),   dim3(256), 0, stream, feats, out);
  hipLaunchKernelGGL(k_mfma,  dim3(256),   dim3(512), 0, stream, feats, cb, out);
  hipLaunchKernelGGL(k_zq,    dim3(16384), dim3(256), 0, stream, cb, out);
}